// Round 5
// baseline (849.359 us; speedup 1.0000x reference)
//
#include <hip/hip_runtime.h>

#define BB 512
#define TT 1024
#define KK 48
#define NINF (-1e30f)

__device__ __forceinline__ float rlane(float v, int l) {
    return __int_as_float(__builtin_amdgcn_readlane(__float_as_int(v), l));
}
__device__ __forceinline__ float rfirst(float v) {
    return __int_as_float(__builtin_amdgcn_readfirstlane(__float_as_int(v)));
}

// One 64-thread block per batch. ONE wave runs BOTH scans interleaved:
//   - Viterbi in log domain (bit-exact vs reference)
//   - forward in EXP domain: p' = (sum_i p_i * E_ij) * exp(e_j), renorm
//     every 4 steps by lane-0 p, accumulating C += log(m).
// Two independent dependency chains in one instruction stream hide each
// other's latency (1 wave/SIMD has nothing else to overlap with).
__global__ __launch_bounds__(64, 1) void crf_main(
    const float* __restrict__ em,    // [B][T][K]
    const int*   __restrict__ tags,  // [B][T]
    const float* __restrict__ st,    // [K]
    const float* __restrict__ en,    // [K]
    const float* __restrict__ tr,    // [K][K]
    float* __restrict__ out,         // [1 + B*T]
    float* __restrict__ ws)          // [B]
{
    __shared__ unsigned char s_bp[TT][KK];      // 49152 B (row 0 unused)
    __shared__ unsigned char s_path[TT];        // 1024 B

    const int b    = blockIdx.x;
    const int lane = threadIdx.x & 63;

    const float* emb = em + (size_t)b * TT * KK;
    const int*   tgb = tags + (size_t)b * TT;

    // sequence length (mask is a contiguous prefix)
    int cnt = 0;
    for (int t = lane; t < TT; t += 64) cnt += (tgb[t] > -1) ? 1 : 0;
#pragma unroll
    for (int off = 32; off >= 1; off >>= 1) cnt += __shfl_xor(cnt, off);
    const int len = cnt;  // >= 1

    const bool act = lane < KK;
    const int  jj  = act ? lane : (KK - 1);

    // ---- gold path score: pure gather, t-parallel across lanes ----
    float sc = 0.f;
    for (int t = lane; t < len; t += 64) {
        int tg = tgb[t];
        sc += emb[t * KK + tg];
        if (t > 0) sc += tr[tgb[t - 1] * KK + tg];
    }
#pragma unroll
    for (int off = 32; off >= 1; off >>= 1) sc += __shfl_xor(sc, off);
    const float score = sc + st[tgb[0]] + en[tgb[len - 1]];  // lane-uniform

    // ---- register columns ----
    float Tc[KK], eTc[KK];   // T[:, j] and exp(T[:, j])
#pragma unroll
    for (int i = 0; i < KK; ++i) {
        float tv = tr[i * KK + jj];
        Tc[i]  = tv;
        eTc[i] = __expf(tv);
    }

    // ---- init ----
    float a0 = st[jj] + emb[jj];
    float av = act ? a0 : NINF;          // viterbi alpha (log domain)
    float C  = rfirst(a0);               // forward log-offset
    float p  = act ? __expf(a0 - C) : 0.f;  // forward alpha (exp domain)

    const int S    = len - 1;
    const int nblk = S >> 2;
    const int rem  = S & 3;

    float e[4];
#pragma unroll
    for (int k = 0; k < 4; ++k) {
        int tn = 1 + k; tn = (tn < len) ? tn : (len - 1);
        e[k] = emb[(size_t)tn * KK + jj];
    }

#define STEP(t_, k_, RENORM) {                                               \
        const float eS = e[k_];                                              \
        /* ---------- viterbi (bit-exact) ---------- */                      \
        float x[KK];                                                         \
        _Pragma("unroll")                                                    \
        for (int i = 0; i < KK; ++i) x[i] = rlane(av, i) + Tc[i];            \
        float l1[16];                                                        \
        _Pragma("unroll")                                                    \
        for (int q = 0; q < 16; ++q)                                         \
            l1[q] = fmaxf(fmaxf(x[3 * q], x[3 * q + 1]), x[3 * q + 2]);      \
        float l2[6];                                                         \
        _Pragma("unroll")                                                    \
        for (int q = 0; q < 5; ++q)                                          \
            l2[q] = fmaxf(fmaxf(l1[3 * q], l1[3 * q + 1]), l1[3 * q + 2]);   \
        l2[5] = l1[15];                                                      \
        float M = fmaxf(fmaxf(fmaxf(l2[0], l2[1]), l2[2]),                   \
                        fmaxf(fmaxf(l2[3], l2[4]), l2[5]));                  \
        int bi0 = 255, bi1 = 255, bi2 = 255, bi3 = 255;                      \
        _Pragma("unroll")                                                    \
        for (int i = 11; i >= 0; --i) {                                      \
            bi0 = (x[i]      == M) ? (i)      : bi0;                         \
            bi1 = (x[i + 12] == M) ? (i + 12) : bi1;                         \
            bi2 = (x[i + 24] == M) ? (i + 24) : bi2;                         \
            bi3 = (x[i + 36] == M) ? (i + 36) : bi3;                         \
        }                                                                    \
        int bi = min(min(bi0, bi1), min(bi2, bi3));                          \
        av = act ? (M + eS) : NINF;                                          \
        if (act) s_bp[t_][lane] = (unsigned char)bi;                         \
        /* ---------- forward (exp domain) ---------- */                     \
        float z0 = 0.f, z1 = 0.f, z2 = 0.f, z3 = 0.f;                        \
        _Pragma("unroll")                                                    \
        for (int q = 0; q < 12; ++q) {                                       \
            z0 = fmaf(rlane(p, 4 * q + 0), eTc[4 * q + 0], z0);              \
            z1 = fmaf(rlane(p, 4 * q + 1), eTc[4 * q + 1], z1);              \
            z2 = fmaf(rlane(p, 4 * q + 2), eTc[4 * q + 2], z2);              \
            z3 = fmaf(rlane(p, 4 * q + 3), eTc[4 * q + 3], z3);              \
        }                                                                    \
        p = ((z0 + z1) + (z2 + z3)) * __expf(eS);                            \
        if (RENORM) {                                                        \
            float m = rfirst(p);                                             \
            p *= __frcp_rn(m);                                               \
            C += __logf(m);                                                  \
        }                                                                    \
        /* ---------- prefetch ---------- */                                 \
        int tn = (t_) + 4; tn = (tn < len) ? tn : (len - 1);                 \
        e[k_] = emb[(size_t)tn * KK + jj];                                   \
    }

    for (int u = 0; u < nblk; ++u) {
        int t = 4 * u + 1;
        STEP(t, 0, 0) STEP(t + 1, 1, 0) STEP(t + 2, 2, 0) STEP(t + 3, 3, 1)
    }
    {
        int t = (nblk << 2) + 1;
        if (rem > 0) STEP(t, 0, 0)
        if (rem > 1) STEP(t + 1, 1, 0)
        if (rem > 2) STEP(t + 2, 2, 0)
    }
#undef STEP

    // ---- forward finish: logZ = C + log(sum_j p_j * exp(en_j)) ----
    {
        float y = act ? (p * __expf(en[jj])) : 0.f;
#pragma unroll
        for (int off = 32; off >= 1; off >>= 1) y += __shfl_xor(y, off);
        float logz = C + __logf(y);
        if (lane == 0) ws[b] = score - logz;
    }

    // ---- viterbi finish: best last tag, backtrack, write ----
    {
        float v = act ? (av + en[jj]) : NINF;
        float M = v;
#pragma unroll
        for (int off = 32; off >= 1; off >>= 1) M = fmaxf(M, __shfl_xor(M, off));
        unsigned long long msk = __ballot(v == M);
        int cur = __ffsll(msk) - 1;
        s_path[len - 1] = (unsigned char)cur;

        // register-row backtrack: lane l holds bp[t][l]; serial step is a
        // readlane (VALU) instead of a dependent LDS load. 8-row batches.
        int t = len - 1;
        while (t >= 1) {
            const int n = (t < 8) ? t : 8;
            unsigned r[8];
#pragma unroll
            for (int k = 0; k < 8; ++k)
                r[k] = (k < n && act) ? (unsigned)s_bp[t - k][lane] : 0u;
#pragma unroll
            for (int k = 0; k < 8; ++k) {
                if (k < n) {
                    cur = __builtin_amdgcn_readlane((int)r[k], cur);
                    if (lane == 0) s_path[t - k - 1] = (unsigned char)cur;
                }
            }
            t -= n;
        }

        float* ob = out + 1 + (size_t)b * TT;
        for (int tt = lane; tt < TT; tt += 64)
            ob[tt] = (tt < len) ? (float)s_path[tt] : -1.0f;
    }
}

__global__ __launch_bounds__(512) void loss_reduce(const float* __restrict__ ws,
                                                   float* __restrict__ out)
{
    __shared__ float sh[8];
    const int lane = threadIdx.x & 63;
    const int w    = threadIdx.x >> 6;
    float s = ws[threadIdx.x];  // B == 512 == blockDim
#pragma unroll
    for (int off = 32; off >= 1; off >>= 1) s += __shfl_xor(s, off);
    if (lane == 0) sh[w] = s;
    __syncthreads();
    if (threadIdx.x == 0) {
        float tot = 0.f;
        for (int i = 0; i < 8; ++i) tot += sh[i];
        out[0] = -tot;
    }
}

extern "C" void kernel_launch(void* const* d_in, const int* in_sizes, int n_in,
                              void* d_out, int out_size, void* d_ws, size_t ws_size,
                              hipStream_t stream)
{
    const float* em   = (const float*)d_in[0];
    const int*   tags = (const int*)d_in[1];
    const float* st   = (const float*)d_in[2];
    const float* en   = (const float*)d_in[3];
    const float* tr   = (const float*)d_in[4];
    float* out = (float*)d_out;
    float* wsf = (float*)d_ws;

    hipLaunchKernelGGL(crf_main, dim3(BB), dim3(64), 0, stream,
                       em, tags, st, en, tr, out, wsf);
    hipLaunchKernelGGL(loss_reduce, dim3(1), dim3(512), 0, stream, wsf, out);
}

// Round 6
// 638.648 us; speedup vs baseline: 1.3299x; 1.3299x over previous
//
#include <hip/hip_runtime.h>

#define BB 512
#define TT 1024
#define KK 48
#define NINF (-1e30f)

__device__ __forceinline__ float rfirst(float v) {
    return __int_as_float(__builtin_amdgcn_readfirstlane(__float_as_int(v)));
}
// broadcast lane (i4/4) to all lanes through the LDS crossbar (VGPR->VGPR,
// LDS pipe, no SGPR round-trip). i4 is a compile-time constant 4*i.
__device__ __forceinline__ float bcast(float v, int i4) {
    return __int_as_float(__builtin_amdgcn_ds_bpermute(i4, __float_as_int(v)));
}

// One block per batch. Wave 0: forward (log-partition + gold score -> ws[b]).
// Wave 1: Viterbi (backpointers in LDS, backtrack, write tags to out[1..]).
// Inner loops contain NO v_readlane and NO v_cmp/vcc round-trips.
__global__ __launch_bounds__(128, 1) void crf_main(
    const float* __restrict__ em,    // [B][T][K]
    const int*   __restrict__ tags,  // [B][T]
    const float* __restrict__ st,    // [K]
    const float* __restrict__ en,    // [K]
    const float* __restrict__ tr,    // [K][K]
    float* __restrict__ out,         // [1 + B*T]
    float* __restrict__ ws)          // [B]
{
    __shared__ unsigned char s_bp[TT][KK];      // 49152 B (row 0 unused)
    __shared__ unsigned char s_path[TT];        // 1024 B

    const int b    = blockIdx.x;
    const int tid  = threadIdx.x;
    const int lane = tid & 63;
    const int wid  = tid >> 6;

    const float* emb = em + (size_t)b * TT * KK;
    const int*   tgb = tags + (size_t)b * TT;

    // sequence length (mask is a contiguous prefix)
    int cnt = 0;
    for (int t = lane; t < TT; t += 64) cnt += (tgb[t] > -1) ? 1 : 0;
#pragma unroll
    for (int off = 32; off >= 1; off >>= 1) cnt += __shfl_xor(cnt, off);
    const int len = cnt;  // >= 1

    const bool act = lane < KK;
    const int  jj  = act ? lane : (KK - 1);

    const int S    = len - 1;
    const int nblk = S >> 2;
    const int rem  = S & 3;

    if (wid == 0) {
        // ---- gold path score: pure gather, t-parallel across lanes ----
        float sc = 0.f;
        for (int t = lane; t < len; t += 64) {
            int tg = tgb[t];
            sc += emb[t * KK + tg];
            if (t > 0) sc += tr[tgb[t - 1] * KK + tg];
        }
#pragma unroll
        for (int off = 32; off >= 1; off >>= 1) sc += __shfl_xor(sc, off);
        const float score = sc + st[tgb[0]] + en[tgb[len - 1]];

        // ---- forward scan, exp domain ----
        float eTc[KK];  // exp(T[:, j])
#pragma unroll
        for (int i = 0; i < KK; ++i) eTc[i] = __expf(tr[i * KK + jj]);

        float a0 = st[jj] + emb[jj];
        float C  = rfirst(a0);
        float p  = __expf(a0 - C);   // lanes 48-63 mirror lane 47 (never read)

        float e[4];
#pragma unroll
        for (int k = 0; k < 4; ++k) {
            int tn = 1 + k; tn = (tn < len) ? tn : (len - 1);
            e[k] = emb[(size_t)tn * KK + jj];
        }

#define FSTEP(t_, k_, RENORM) {                                              \
        const float eS = e[k_];                                              \
        float z0 = 0.f, z1 = 0.f, z2 = 0.f, z3 = 0.f;                        \
        _Pragma("unroll")                                                    \
        for (int q = 0; q < 12; ++q) {                                       \
            z0 = fmaf(bcast(p, 4 * (4 * q + 0)), eTc[4 * q + 0], z0);        \
            z1 = fmaf(bcast(p, 4 * (4 * q + 1)), eTc[4 * q + 1], z1);        \
            z2 = fmaf(bcast(p, 4 * (4 * q + 2)), eTc[4 * q + 2], z2);        \
            z3 = fmaf(bcast(p, 4 * (4 * q + 3)), eTc[4 * q + 3], z3);        \
        }                                                                    \
        p = ((z0 + z1) + (z2 + z3)) * __expf(eS);                            \
        if (RENORM) {                                                        \
            float m = rfirst(p);                                             \
            p *= __frcp_rn(m);                                               \
            C += __logf(m);                                                  \
        }                                                                    \
        int tn = (t_) + 4; tn = (tn < len) ? tn : (len - 1);                 \
        e[k_] = emb[(size_t)tn * KK + jj];                                   \
    }

        for (int u = 0; u < nblk; ++u) {
            int t = 4 * u + 1;
            FSTEP(t, 0, 0) FSTEP(t + 1, 1, 0) FSTEP(t + 2, 2, 0) FSTEP(t + 3, 3, 1)
        }
        {
            int t = (nblk << 2) + 1;
            if (rem > 0) FSTEP(t, 0, 0)
            if (rem > 1) FSTEP(t + 1, 1, 0)
            if (rem > 2) FSTEP(t + 2, 2, 0)
        }
#undef FSTEP

        // logZ = C + log(sum_j p_j * exp(en_j))
        float y = act ? (p * __expf(en[jj])) : 0.f;
#pragma unroll
        for (int off = 32; off >= 1; off >>= 1) y += __shfl_xor(y, off);
        float logz = C + __logf(y);
        if (lane == 0) ws[b] = score - logz;
    } else {
        // ---------------- viterbi (bit-exact vs reference) ----------------
        float Tc[KK];  // T[:, j]
#pragma unroll
        for (int i = 0; i < KK; ++i) Tc[i] = tr[i * KK + jj];

        float av = st[jj] + emb[jj];   // lanes 48-63 mirror lane 47

        float e[4];
#pragma unroll
        for (int k = 0; k < 4; ++k) {
            int tn = 1 + k; tn = (tn < len) ? tn : (len - 1);
            e[k] = emb[(size_t)tn * KK + jj];
        }

#define VSTEP(t_, k_) {                                                      \
        const float eS = e[k_];                                              \
        float x[KK];                                                         \
        _Pragma("unroll")                                                    \
        for (int i = 0; i < KK; ++i) x[i] = bcast(av, 4 * i) + Tc[i];        \
        /* exact max: 3-way fmax tree (compiler emits v_max3) */             \
        float l1[16];                                                        \
        _Pragma("unroll")                                                    \
        for (int q = 0; q < 16; ++q)                                         \
            l1[q] = fmaxf(fmaxf(x[3 * q], x[3 * q + 1]), x[3 * q + 2]);      \
        float l2[6];                                                         \
        _Pragma("unroll")                                                    \
        for (int q = 0; q < 5; ++q)                                          \
            l2[q] = fmaxf(fmaxf(l1[3 * q], l1[3 * q + 1]), l1[3 * q + 2]);   \
        l2[5] = l1[15];                                                      \
        float M = fmaxf(fmaxf(fmaxf(l2[0], l2[1]), l2[2]),                   \
                        fmaxf(fmaxf(l2[3], l2[4]), l2[5]));                  \
        /* first-occurrence argmax, vcc-free: key=(min(d,1)<<6)|i, min */    \
        const int Mi = __float_as_int(M);                                    \
        unsigned k0 = ~0u, k1 = ~0u, k2 = ~0u, k3 = ~0u,                     \
                 k4 = ~0u, k5 = ~0u, k6 = ~0u, k7 = ~0u;                     \
        _Pragma("unroll")                                                    \
        for (int i = 0; i < 6; ++i) {                                        \
            unsigned d0 = (unsigned)(__float_as_int(x[i])      ^ Mi);        \
            unsigned d1 = (unsigned)(__float_as_int(x[i + 6])  ^ Mi);        \
            unsigned d2 = (unsigned)(__float_as_int(x[i + 12]) ^ Mi);        \
            unsigned d3 = (unsigned)(__float_as_int(x[i + 18]) ^ Mi);        \
            unsigned d4 = (unsigned)(__float_as_int(x[i + 24]) ^ Mi);        \
            unsigned d5 = (unsigned)(__float_as_int(x[i + 30]) ^ Mi);        \
            unsigned d6 = (unsigned)(__float_as_int(x[i + 36]) ^ Mi);        \
            unsigned d7 = (unsigned)(__float_as_int(x[i + 42]) ^ Mi);        \
            k0 = min(k0, (min(d0, 1u) << 6) | (unsigned)(i));                \
            k1 = min(k1, (min(d1, 1u) << 6) | (unsigned)(i + 6));            \
            k2 = min(k2, (min(d2, 1u) << 6) | (unsigned)(i + 12));           \
            k3 = min(k3, (min(d3, 1u) << 6) | (unsigned)(i + 18));           \
            k4 = min(k4, (min(d4, 1u) << 6) | (unsigned)(i + 24));           \
            k5 = min(k5, (min(d5, 1u) << 6) | (unsigned)(i + 30));           \
            k6 = min(k6, (min(d6, 1u) << 6) | (unsigned)(i + 36));           \
            k7 = min(k7, (min(d7, 1u) << 6) | (unsigned)(i + 42));           \
        }                                                                    \
        unsigned bi = min(min(min(k0, k1), min(k2, k3)),                     \
                          min(min(k4, k5), min(k6, k7)));                    \
        av = M + eS;                                                         \
        if (act) s_bp[t_][lane] = (unsigned char)bi;                         \
        int tn = (t_) + 4; tn = (tn < len) ? tn : (len - 1);                 \
        e[k_] = emb[(size_t)tn * KK + jj];                                   \
    }

        for (int u = 0; u < nblk; ++u) {
            int t = 4 * u + 1;
            VSTEP(t, 0) VSTEP(t + 1, 1) VSTEP(t + 2, 2) VSTEP(t + 3, 3)
        }
        {
            int t = (nblk << 2) + 1;
            if (rem > 0) VSTEP(t, 0)
            if (rem > 1) VSTEP(t + 1, 1)
            if (rem > 2) VSTEP(t + 2, 2)
        }
#undef VSTEP

        // best last tag = argmax(alpha + end), first occurrence
        float v = act ? (av + en[jj]) : NINF;
        float M = v;
#pragma unroll
        for (int off = 32; off >= 1; off >>= 1) M = fmaxf(M, __shfl_xor(M, off));
        unsigned long long msk = __ballot(v == M);
        int cur = __ffsll(msk) - 1;
        s_path[len - 1] = (unsigned char)cur;

        // register-row backtrack: lane l holds bp[t][l]; serial step is a
        // readlane instead of a dependent LDS load. 8-row batches.
        int t = len - 1;
        while (t >= 1) {
            const int n = (t < 8) ? t : 8;
            unsigned r[8];
#pragma unroll
            for (int k = 0; k < 8; ++k)
                r[k] = (k < n && act) ? (unsigned)s_bp[t - k][lane] : 0u;
#pragma unroll
            for (int k = 0; k < 8; ++k) {
                if (k < n) {
                    cur = __builtin_amdgcn_readlane((int)r[k], cur);
                    if (lane == 0) s_path[t - k - 1] = (unsigned char)cur;
                }
            }
            t -= n;
        }

        float* ob = out + 1 + (size_t)b * TT;
        for (int tt = lane; tt < TT; tt += 64)
            ob[tt] = (tt < len) ? (float)s_path[tt] : -1.0f;
    }
}

__global__ __launch_bounds__(512) void loss_reduce(const float* __restrict__ ws,
                                                   float* __restrict__ out)
{
    __shared__ float sh[8];
    const int lane = threadIdx.x & 63;
    const int w    = threadIdx.x >> 6;
    float s = ws[threadIdx.x];  // B == 512 == blockDim
#pragma unroll
    for (int off = 32; off >= 1; off >>= 1) s += __shfl_xor(s, off);
    if (lane == 0) sh[w] = s;
    __syncthreads();
    if (threadIdx.x == 0) {
        float tot = 0.f;
        for (int i = 0; i < 8; ++i) tot += sh[i];
        out[0] = -tot;
    }
}

extern "C" void kernel_launch(void* const* d_in, const int* in_sizes, int n_in,
                              void* d_out, int out_size, void* d_ws, size_t ws_size,
                              hipStream_t stream)
{
    const float* em   = (const float*)d_in[0];
    const int*   tags = (const int*)d_in[1];
    const float* st   = (const float*)d_in[2];
    const float* en   = (const float*)d_in[3];
    const float* tr   = (const float*)d_in[4];
    float* out = (float*)d_out;
    float* wsf = (float*)d_ws;

    hipLaunchKernelGGL(crf_main, dim3(BB), dim3(128), 0, stream,
                       em, tags, st, en, tr, out, wsf);
    hipLaunchKernelGGL(loss_reduce, dim3(1), dim3(512), 0, stream, wsf, out);
}

// Round 7
// 534.766 us; speedup vs baseline: 1.5883x; 1.1943x over previous
//
#include <hip/hip_runtime.h>

#define BB 512
#define TT 1024
#define KK 48
#define NINF (-1e30f)

__device__ __forceinline__ float rlane(float v, int l) {
    return __int_as_float(__builtin_amdgcn_readlane(__float_as_int(v), l));
}
__device__ __forceinline__ float rfirst(float v) {
    return __int_as_float(__builtin_amdgcn_readfirstlane(__float_as_int(v)));
}

// One block per batch. Wave 0: forward (log-partition + gold score -> ws[b]).
// Wave 1: Viterbi, SOFTWARE-PIPELINED: step t's argmax/backpointer work is
// done inside step t+1's iteration, giving the scheduler ~100 independent
// VALU ops to fill the broadcast->tree->av dependency-chain bubbles.
__global__ __launch_bounds__(128, 1) void crf_main(
    const float* __restrict__ em,    // [B][T][K]
    const int*   __restrict__ tags,  // [B][T]
    const float* __restrict__ st,    // [K]
    const float* __restrict__ en,    // [K]
    const float* __restrict__ tr,    // [K][K]
    float* __restrict__ out,         // [1 + B*T]
    float* __restrict__ ws)          // [B]
{
    __shared__ unsigned char s_bp[TT * KK];     // 49152 B (row 0 unused)
    __shared__ unsigned char s_path[TT];        // 1024 B

    const int b    = blockIdx.x;
    const int tid  = threadIdx.x;
    const int lane = tid & 63;
    const int wid  = tid >> 6;

    const float* emb = em + (size_t)b * TT * KK;
    const int*   tgb = tags + (size_t)b * TT;

    // sequence length (mask is a contiguous prefix)
    int cnt = 0;
    for (int t = lane; t < TT; t += 64) cnt += (tgb[t] > -1) ? 1 : 0;
#pragma unroll
    for (int off = 32; off >= 1; off >>= 1) cnt += __shfl_xor(cnt, off);
    const int len = cnt;  // >= 1

    const bool act = lane < KK;
    const int  jj  = act ? lane : (KK - 1);   // lanes 48-63 mirror lane 47

    const int S = len - 1;   // scan steps

    if (wid == 0) {
        // ---- gold path score: pure gather, t-parallel across lanes ----
        float sc = 0.f;
        for (int t = lane; t < len; t += 64) {
            int tg = tgb[t];
            sc += emb[t * KK + tg];
            if (t > 0) sc += tr[tgb[t - 1] * KK + tg];
        }
#pragma unroll
        for (int off = 32; off >= 1; off >>= 1) sc += __shfl_xor(sc, off);
        const float score = sc + st[tgb[0]] + en[tgb[len - 1]];

        // ---- forward scan, exp domain (validated R5/R6) ----
        float eTc[KK];  // exp(T[:, j])
#pragma unroll
        for (int i = 0; i < KK; ++i) eTc[i] = __expf(tr[i * KK + jj]);

        float a0 = st[jj] + emb[jj];
        float C  = rfirst(a0);
        float p  = __expf(a0 - C);

        float e[2];
        {
            int t1 = (1 < len) ? 1 : (len - 1);
            int t2 = (2 < len) ? 2 : (len - 1);
            e[1] = emb[(size_t)t1 * KK + jj];
            e[0] = emb[(size_t)t2 * KK + jj];
        }

#define FSTEP(t_, RENORM) {                                                  \
        const float eS = e[(t_) & 1];                                        \
        float z0 = 0.f, z1 = 0.f, z2 = 0.f, z3 = 0.f;                        \
        float z4 = 0.f, z5 = 0.f, z6 = 0.f, z7 = 0.f;                        \
        _Pragma("unroll")                                                    \
        for (int q = 0; q < 6; ++q) {                                        \
            z0 = fmaf(rlane(p, 8 * q + 0), eTc[8 * q + 0], z0);              \
            z1 = fmaf(rlane(p, 8 * q + 1), eTc[8 * q + 1], z1);              \
            z2 = fmaf(rlane(p, 8 * q + 2), eTc[8 * q + 2], z2);              \
            z3 = fmaf(rlane(p, 8 * q + 3), eTc[8 * q + 3], z3);              \
            z4 = fmaf(rlane(p, 8 * q + 4), eTc[8 * q + 4], z4);              \
            z5 = fmaf(rlane(p, 8 * q + 5), eTc[8 * q + 5], z5);              \
            z6 = fmaf(rlane(p, 8 * q + 6), eTc[8 * q + 6], z6);              \
            z7 = fmaf(rlane(p, 8 * q + 7), eTc[8 * q + 7], z7);              \
        }                                                                    \
        p = (((z0 + z1) + (z2 + z3)) + ((z4 + z5) + (z6 + z7)))              \
            * __expf(eS);                                                    \
        if (RENORM) {                                                        \
            float m = rfirst(p);                                             \
            p *= __frcp_rn(m);                                               \
            C += __logf(m);                                                  \
        }                                                                    \
        int tn = (t_) + 2; tn = (tn < len) ? tn : (len - 1);                 \
        e[(t_) & 1] = emb[(size_t)tn * KK + jj];                             \
    }

        {
            int t = 1;
            for (; t + 4 <= S + 1; t += 4) {
                FSTEP(t, 0) FSTEP(t + 1, 0) FSTEP(t + 2, 0) FSTEP(t + 3, 1)
            }
            for (; t <= S; ++t) FSTEP(t, 1)
        }
#undef FSTEP

        // logZ = C + log(sum_j p_j * exp(en_j))
        float y = act ? (p * __expf(en[jj])) : 0.f;
#pragma unroll
        for (int off = 32; off >= 1; off >>= 1) y += __shfl_xor(y, off);
        float logz = C + __logf(y);
        if (lane == 0) ws[b] = score - logz;
    } else {
        // ---------------- viterbi (bit-exact vs reference) ----------------
        float Tc[KK];  // T[:, j]
#pragma unroll
        for (int i = 0; i < KK; ++i) Tc[i] = tr[i * KK + jj];

        float av = st[jj] + emb[jj];

        float e[2];
        {
            int t1 = (1 < len) ? 1 : (len - 1);
            int t2 = (2 < len) ? 2 : (len - 1);
            e[1] = emb[(size_t)t1 * KK + jj];
            e[0] = emb[(size_t)t2 * KK + jj];
        }

        float xA[KK], xB[KK];
        float MA = 0.f, MB = 0.f;

// broadcast + add + exact max tree + recurrence update (critical chain)
#define MAXPHASE(X, MV, t_) {                                                \
        const float eS = e[(t_) & 1];                                        \
        _Pragma("unroll")                                                    \
        for (int i = 0; i < KK; ++i) X[i] = rlane(av, i) + Tc[i];            \
        float l1[16];                                                        \
        _Pragma("unroll")                                                    \
        for (int q = 0; q < 16; ++q)                                         \
            l1[q] = fmaxf(fmaxf(X[3 * q], X[3 * q + 1]), X[3 * q + 2]);      \
        float l2[6];                                                         \
        _Pragma("unroll")                                                    \
        for (int q = 0; q < 5; ++q)                                          \
            l2[q] = fmaxf(fmaxf(l1[3 * q], l1[3 * q + 1]), l1[3 * q + 2]);   \
        l2[5] = l1[15];                                                      \
        MV = fmaxf(fmaxf(fmaxf(l2[0], l2[1]), l2[2]),                        \
                   fmaxf(fmaxf(l2[3], l2[4]), l2[5]));                       \
        av = MV + eS;                                                        \
        int tn = (t_) + 2; tn = (tn < len) ? tn : (len - 1);                 \
        e[(t_) & 1] = emb[(size_t)tn * KK + jj];                             \
    }

// first-occurrence argmax + backpointer store (off the critical chain;
// scheduled into the NEXT step's latency bubbles). Descending selects:
// last-applied (smallest i) wins within each block; min across blocks.
#define ARGPHASE(X, MV, t_) {                                                \
        int a0 = 255, a1 = 255, a2 = 255, a3 = 255;                          \
        _Pragma("unroll")                                                    \
        for (int i = 11; i >= 0; --i) {                                      \
            a0 = (X[i]      == MV) ? (i)      : a0;                          \
            a1 = (X[i + 12] == MV) ? (i + 12) : a1;                          \
            a2 = (X[i + 24] == MV) ? (i + 24) : a2;                          \
            a3 = (X[i + 36] == MV) ? (i + 36) : a3;                          \
        }                                                                    \
        int bi = min(min(a0, a1), min(a2, a3));                              \
        s_bp[(t_) * KK + jj] = (unsigned char)bi;  /* lanes>=48 dup ln47 */  \
    }

        if (S >= 1) {
            int t = 1;
            MAXPHASE(xA, MA, 1)
            while (t + 2 <= S) {
                MAXPHASE(xB, MB, t + 1)
                ARGPHASE(xA, MA, t)
                MAXPHASE(xA, MA, t + 2)
                ARGPHASE(xB, MB, t + 1)
                t += 2;
            }
            if (t + 1 <= S) {
                MAXPHASE(xB, MB, t + 1)
                ARGPHASE(xA, MA, t)
                ARGPHASE(xB, MB, t + 1)
            } else {
                ARGPHASE(xA, MA, t)
            }
        }
#undef MAXPHASE
#undef ARGPHASE

        // best last tag = argmax(alpha + end), first occurrence
        float v = act ? (av + en[jj]) : NINF;
        float M = v;
#pragma unroll
        for (int off = 32; off >= 1; off >>= 1) M = fmaxf(M, __shfl_xor(M, off));
        unsigned long long msk = __ballot(v == M);
        int cur = __ffsll(msk) - 1;
        s_path[len - 1] = (unsigned char)cur;   // cur uniform

        // register-row backtrack: lane l holds bp[t][l]; serial step is a
        // readlane instead of a dependent LDS load. 8-row batches.
        int t = len - 1;
        while (t >= 1) {
            const int n = (t < 8) ? t : 8;
            unsigned r[8];
#pragma unroll
            for (int k = 0; k < 8; ++k)
                r[k] = (k < n) ? (unsigned)s_bp[(t - k) * KK + jj] : 0u;
#pragma unroll
            for (int k = 0; k < 8; ++k) {
                if (k < n) {
                    cur = __builtin_amdgcn_readlane((int)r[k], cur);
                    if (lane == 0) s_path[t - k - 1] = (unsigned char)cur;
                }
            }
            t -= n;
        }

        // write tags (as floats; -1 where masked)
        float* ob = out + 1 + (size_t)b * TT;
        for (int tt = lane; tt < TT; tt += 64)
            ob[tt] = (tt < len) ? (float)s_path[tt] : -1.0f;
    }
}

__global__ __launch_bounds__(512) void loss_reduce(const float* __restrict__ ws,
                                                   float* __restrict__ out)
{
    __shared__ float sh[8];
    const int lane = threadIdx.x & 63;
    const int w    = threadIdx.x >> 6;
    float s = ws[threadIdx.x];  // B == 512 == blockDim
#pragma unroll
    for (int off = 32; off >= 1; off >>= 1) s += __shfl_xor(s, off);
    if (lane == 0) sh[w] = s;
    __syncthreads();
    if (threadIdx.x == 0) {
        float tot = 0.f;
        for (int i = 0; i < 8; ++i) tot += sh[i];
        out[0] = -tot;
    }
}

extern "C" void kernel_launch(void* const* d_in, const int* in_sizes, int n_in,
                              void* d_out, int out_size, void* d_ws, size_t ws_size,
                              hipStream_t stream)
{
    const float* em   = (const float*)d_in[0];
    const int*   tags = (const int*)d_in[1];
    const float* st   = (const float*)d_in[2];
    const float* en   = (const float*)d_in[3];
    const float* tr   = (const float*)d_in[4];
    float* out = (float*)d_out;
    float* wsf = (float*)d_ws;

    hipLaunchKernelGGL(crf_main, dim3(BB), dim3(128), 0, stream,
                       em, tags, st, en, tr, out, wsf);
    hipLaunchKernelGGL(loss_reduce, dim3(1), dim3(512), 0, stream, wsf, out);
}